// Round 4
// baseline (179.579 us; speedup 1.0000x reference)
//
#include <hip/hip_runtime.h>

// RoiPooling: crop + bilinear 7x7 resize, TF1 resize_bilinear (align_corners=False).
// feat: (128,128,1024) fp32, rois: (512,4) fp32 [ymin,xmin,ymax,xmax], out: (512,7,7,1024) fp32.
//
// R4 = R3 with the nontemporal-store compile fix (use ext_vector_type(4) float,
// which __builtin_nontemporal_store accepts, instead of HIP's float4 class).
//  - Spatial scheduling: rank ROIs by ymin, each XCD (blockIdx%8) gets a
//    contiguous y-band of 64 ROIs -> L2 sweeps a strip instead of thrashing.
//  - Non-temporal stores: 100 MB write-once output stays out of L2.

#define POOL_P 7
#define FEAT_C 1024
#define FEAT_W 128
#define CELLS_PER_ROI (POOL_P * POOL_P)          // 49
#define NUM_XCD 8

typedef float nfloat4 __attribute__((ext_vector_type(4)));

// ---- Kernel A: perm[rank] = roi index, ranked by ymin (ties by index) ----
__global__ __launch_bounds__(512) void rank_rois_kernel(
    const float* __restrict__ rois, int n, int* __restrict__ perm)
{
    __shared__ float ys[512];
    const int t = threadIdx.x;
    if (t < n) ys[t] = rois[4 * t];              // ymin
    __syncthreads();
    if (t < n) {
        const float y = ys[t];
        int rank = 0;
        for (int j = 0; j < n; ++j) {
            const float yj = ys[j];
            rank += (yj < y) || (yj == y && j < t);
        }
        perm[rank] = t;
    }
}

// ---- Kernel B: one block per (rank, cell), XCD-banded ----
__global__ __launch_bounds__(128) void roi_pool_kernel(
    const float* __restrict__ feat,
    const float* __restrict__ rois,
    const int* __restrict__ perm,
    float* __restrict__ out,
    int n_rois, int ranks_per_xcd)
{
    const int i = blockIdx.x;
    const int k = i & (NUM_XCD - 1);             // XCD id (heuristic: blockIdx%8)
    const int j = i >> 3;                        // work item within XCD
    const int rank_local = j / CELLS_PER_ROI;
    const int cell = j - rank_local * CELLS_PER_ROI;
    const int rank = k * ranks_per_xcd + rank_local;
    if (rank >= n_rois) return;
    const int r = perm[rank];

    const int px = cell % POOL_P;
    const int py = cell / POOL_P;

    // ---- ROI box (wave-uniform scalar math)
    const float4 roi = ((const float4*)rois)[r];
    const int ymin = (int)roi.x;
    const int xmin = (int)roi.y;
    const int ymax = (int)roi.z;
    const int xmax = (int)roi.w;

    const float h = (float)(ymax - ymin + 1);
    const float w = (float)(xmax - xmin + 1);

    const float src_y = (float)py * (h / 7.0f);
    const float src_x = (float)px * (w / 7.0f);

    const int y0 = (int)floorf(src_y);
    const int x0 = (int)floorf(src_x);
    const int y1 = min(y0 + 1, ymax - ymin);
    const int x1 = min(x0 + 1, xmax - xmin);

    const float fy = src_y - (float)y0;
    const float fx = src_x - (float)x0;

    const int gy0 = ymin + y0;
    const int gy1 = ymin + y1;
    const int gx0 = xmin + x0;
    const int gx1 = xmin + x1;

    const nfloat4* __restrict__ tlp = (const nfloat4*)(feat + ((size_t)(gy0 * FEAT_W + gx0)) * FEAT_C);
    const nfloat4* __restrict__ trp = (const nfloat4*)(feat + ((size_t)(gy0 * FEAT_W + gx1)) * FEAT_C);
    const nfloat4* __restrict__ blp = (const nfloat4*)(feat + ((size_t)(gy1 * FEAT_W + gx0)) * FEAT_C);
    const nfloat4* __restrict__ brp = (const nfloat4*)(feat + ((size_t)(gy1 * FEAT_W + gx1)) * FEAT_C);
    nfloat4* __restrict__ op = (nfloat4*)(out + ((size_t)r * CELLS_PER_ROI + cell) * FEAT_C);

    const int t0 = threadIdx.x;                  // [0,128)
    const int t1 = t0 + 128;

    // Issue all 8 loads before any use (max outstanding vmcnt)
    const nfloat4 tl0 = tlp[t0];
    const nfloat4 tr0 = trp[t0];
    const nfloat4 bl0 = blp[t0];
    const nfloat4 br0 = brp[t0];
    const nfloat4 tl1 = tlp[t1];
    const nfloat4 tr1 = trp[t1];
    const nfloat4 bl1 = blp[t1];
    const nfloat4 br1 = brp[t1];

    nfloat4 top0 = tl0 + (tr0 - tl0) * fx;
    nfloat4 bot0 = bl0 + (br0 - bl0) * fx;
    nfloat4 res0 = top0 + (bot0 - top0) * fy;
    nfloat4 top1 = tl1 + (tr1 - tl1) * fx;
    nfloat4 bot1 = bl1 + (br1 - bl1) * fx;
    nfloat4 res1 = top1 + (bot1 - top1) * fy;

    __builtin_nontemporal_store(res0, &op[t0]);
    __builtin_nontemporal_store(res1, &op[t1]);
}

extern "C" void kernel_launch(void* const* d_in, const int* in_sizes, int n_in,
                              void* d_out, int out_size, void* d_ws, size_t ws_size,
                              hipStream_t stream) {
    const float* feat = (const float*)d_in[0];   // (1,128,128,1024) fp32
    const float* rois = (const float*)d_in[1];   // (512,4) fp32
    float* out        = (float*)d_out;           // (512, 7*7*1024) fp32
    int*   perm       = (int*)d_ws;              // 512 ints of scratch

    const int n_rois        = in_sizes[1] / 4;                    // 512
    const int ranks_per_xcd = (n_rois + NUM_XCD - 1) / NUM_XCD;   // 64
    const int n_blocks      = NUM_XCD * ranks_per_xcd * CELLS_PER_ROI; // 25088

    rank_rois_kernel<<<1, 512, 0, stream>>>(rois, n_rois, perm);
    roi_pool_kernel<<<n_blocks, 128, 0, stream>>>(feat, rois, perm, out,
                                                  n_rois, ranks_per_xcd);
}

// Round 5
// 173.091 us; speedup vs baseline: 1.0375x; 1.0375x over previous
//
#include <hip/hip_runtime.h>

// RoiPooling: crop + bilinear 7x7 resize, TF1 resize_bilinear (align_corners=False).
// feat: (128,128,1024) fp32, rois: (512,4) fp32 [ymin,xmin,ymax,xmax], out: (512,7,7,1024) fp32.
//
// R5 changes vs R4:
//  - Dropped rank kernel + y-banding (measured +9us regression, no visible gain).
//  - One block per (roi, py) ROW of 7 cells: 3584 blocks x 256 threads.
//    Amortizes ROI setup, keeps gy0/gy1 row bases fixed per block.
//  - Depth-1 software prefetch over the px loop: issue px+1's 4 corner loads
//    before computing px -> ~8 loads in flight per thread steady-state
//    (R2 was 8-then-drain per tiny one-shot block; latency-bound at 10 B/cyc/CU).
//  - Keep ROI-group XCD swizzle (free) and non-temporal stores.

#define POOL_P 7
#define FEAT_C 1024
#define FEAT_W 128
#define CELLS_PER_ROI (POOL_P * POOL_P)              // 49
#define ROWS_PER_GROUP (8 * POOL_P)                  // 56: 8 ROIs x 7 rows

typedef float nfloat4 __attribute__((ext_vector_type(4)));

__global__ __launch_bounds__(256) void roi_pool_row_kernel(
    const float* __restrict__ feat,
    const float* __restrict__ rois,
    float* __restrict__ out)
{
    // ---- XCD swizzle: keep all 7 row-blocks of one ROI on the same blockIdx%8 slot
    const int i  = blockIdx.x;
    const int q  = i / ROWS_PER_GROUP;               // group of 8 ROIs
    const int k  = i - q * ROWS_PER_GROUP;           // [0,56)
    const int r  = 8 * q + (k & 7);                  // ROI id
    const int py = k >> 3;                           // [0,7)

    // ---- ROI box (wave-uniform)
    const float4 roi = ((const float4*)rois)[r];
    const int ymin = (int)roi.x;
    const int xmin = (int)roi.y;
    const int ymax = (int)roi.z;
    const int xmax = (int)roi.w;

    const float h = (float)(ymax - ymin + 1);
    const float w = (float)(xmax - xmin + 1);

    const float src_y = (float)py * (h / 7.0f);
    const int   y0    = (int)floorf(src_y);
    const int   y1    = min(y0 + 1, ymax - ymin);
    const float fy    = src_y - (float)y0;

    const float* __restrict__ row0 = feat + (size_t)((ymin + y0) * FEAT_W) * FEAT_C;
    const float* __restrict__ row1 = feat + (size_t)((ymin + y1) * FEAT_W) * FEAT_C;

    const float wdiv7 = w / 7.0f;
    const int   xspan = xmax - xmin;

    const int t = threadIdx.x;                       // [0,256): one float4 of 1024 ch
    float* __restrict__ outp = out + ((size_t)r * CELLS_PER_ROI + (size_t)py * POOL_P) * FEAT_C;

    // x-geometry for a given px (all wave-uniform scalar math)
    auto calcx = [&](int px, int& gx0, int& gx1, float& fx) {
        const float sx = (float)px * wdiv7;
        const int   x0 = (int)floorf(sx);
        const int   x1 = min(x0 + 1, xspan);
        fx  = sx - (float)x0;
        gx0 = xmin + x0;
        gx1 = xmin + x1;
    };

    // ---- prologue: issue px=0 loads
    int gx0, gx1; float fx;
    calcx(0, gx0, gx1, fx);
    nfloat4 tl = ((const nfloat4*)(row0 + (size_t)gx0 * FEAT_C))[t];
    nfloat4 tr = ((const nfloat4*)(row0 + (size_t)gx1 * FEAT_C))[t];
    nfloat4 bl = ((const nfloat4*)(row1 + (size_t)gx0 * FEAT_C))[t];
    nfloat4 br = ((const nfloat4*)(row1 + (size_t)gx1 * FEAT_C))[t];

#pragma unroll
    for (int px = 0; px < POOL_P; ++px) {
        nfloat4 ntl, ntr, nbl, nbr; float nfx = 0.f;
        if (px < POOL_P - 1) {
            int ngx0, ngx1;
            calcx(px + 1, ngx0, ngx1, nfx);
            // issue next cell's loads BEFORE waiting on current (prefetch depth 1)
            ntl = ((const nfloat4*)(row0 + (size_t)ngx0 * FEAT_C))[t];
            ntr = ((const nfloat4*)(row0 + (size_t)ngx1 * FEAT_C))[t];
            nbl = ((const nfloat4*)(row1 + (size_t)ngx0 * FEAT_C))[t];
            nbr = ((const nfloat4*)(row1 + (size_t)ngx1 * FEAT_C))[t];
        }

        const nfloat4 top = tl + (tr - tl) * fx;
        const nfloat4 bot = bl + (br - bl) * fx;
        const nfloat4 res = top + (bot - top) * fy;
        __builtin_nontemporal_store(res, &((nfloat4*)(outp + (size_t)px * FEAT_C))[t]);

        if (px < POOL_P - 1) {
            tl = ntl; tr = ntr; bl = nbl; br = nbr; fx = nfx;
        }
    }
}

extern "C" void kernel_launch(void* const* d_in, const int* in_sizes, int n_in,
                              void* d_out, int out_size, void* d_ws, size_t ws_size,
                              hipStream_t stream) {
    const float* feat = (const float*)d_in[0];   // (1,128,128,1024) fp32
    const float* rois = (const float*)d_in[1];   // (512,4) fp32
    float* out        = (float*)d_out;           // (512, 7*7*1024) fp32

    const int n_rois   = in_sizes[1] / 4;        // 512
    const int n_blocks = n_rois * POOL_P;        // 3584 row-blocks

    roi_pool_row_kernel<<<n_blocks, 256, 0, stream>>>(feat, rois, out);
}